// Round 3
// baseline (9.370 us; speedup 1.0000x reference)
//
#include <hip/hip_runtime.h>
#include <math.h>

#define SQRT_2PI 2.5066282746310002f
#define N_ITERS 100

__global__ __launch_bounds__(64) void linearnet_fused(
    const float* __restrict__ x,    // (1,3)
    const float* __restrict__ u0,   // (1,1)
    const float* __restrict__ repa, // (100,1,1)
    const float* __restrict__ W_e1, // (50,4)
    const float* __restrict__ b_e1, // (50)
    const float* __restrict__ W_e2, // (2,50)
    const float* __restrict__ b_e2, // (2)
    const float* __restrict__ W_x1, // (10,1)
    const float* __restrict__ b_x1, // (10)
    const float* __restrict__ W_x2, // (2,10)
    const float* __restrict__ b_x2, // (2)
    const float* __restrict__ W_n1, // (10,1)
    const float* __restrict__ b_n1, // (10)
    const float* __restrict__ W_n2, // (1,10)
    const float* __restrict__ b_n2, // (1)
    float* __restrict__ out)        // [loss, z[0..99]]
{
    const int lane = threadIdx.x;  // single wave of 64

    // ---- uniform scalar inputs ----
    const float u00 = u0[0];
    const float x0 = x[0], x1 = x[1], x2 = x[2];

    // per-lane repa values (iteration `lane` and `lane+64`)
    const float r_a = repa[lane];
    const float r_b = (lane < N_ITERS - 64) ? repa[lane + 64] : 0.0f;

    // ---- constants that depend only on u0: start their (transcendental)
    //      chain as early as possible so it overlaps everything else ----
    const float ud = (((int)u00 - 1) == 0) ? -1.0f : -4.0f;
    const float sigma = sqrtf(-0.5f / ud);
    const float log_norm_term = logf(sigma * SQRT_2PI);   // = -log(normal)... used as +log below

    // ---- Phase 1: encoder 4->50 relu, lanes 0..49 ----
    float h = 0.0f, we2a = 0.0f, we2b = 0.0f;
    if (lane < 50) {
        const float4 w = *reinterpret_cast<const float4*>(W_e1 + lane * 4);
        h = fmaxf(b_e1[lane] + u00 * w.x + x0 * w.y + x1 * w.z + x2 * w.w, 0.0f);
        we2a = W_e2[lane];
        we2b = W_e2[50 + lane];
    }

    // ---- 50 -> 2 projection via butterfly reduce ----
    float p0 = h * we2a;
    float p1 = h * we2b;
    #pragma unroll
    for (int m = 32; m >= 1; m >>= 1) {
        p0 += __shfl_xor(p0, m, 64);
        p1 += __shfl_xor(p1, m, 64);
    }
    const float mean = p0 + b_e2[0];
    const float var  = p1 + b_e2[1];

    // var-dependent log term: issue NOW so it overlaps phase 2
    const float log_var_term = logf(SQRT_2PI * fabsf(var));

    // ---- compute z's and store them immediately (early write drain) ----
    const float za = mean + r_a * var;
    out[1 + lane] = za;
    float zb = 0.0f;
    if (lane < N_ITERS - 64) {
        zb = mean + r_b * var;
        out[1 + lane + 64] = zb;
    }

    // ---- Phase 2 body: per-lane contribution (-z^2*ud + 200*nrm - r^2/2);
    //      uniform log terms hoisted out of the sum ----
    const float bx20 = b_x2[0], bx21 = b_x2[1], bn20 = b_n2[0];

    auto iter_body = [&](float z, float r) -> float {
        float a0 = bx20, a1 = bx21, nl = bn20;
        #pragma unroll
        for (int j = 0; j < 10; ++j) {
            const float hj = z * W_x1[j] + b_x1[j];
            a0 += hj * W_x2[j];
            a1 += hj * W_x2[10 + j];
        }
        #pragma unroll
        for (int j = 0; j < 10; ++j) {
            const float hj = fmaxf(z * W_n1[j] + b_n1[j], 0.0f);
            nl += hj * W_n2[j];
        }
        const float d0 = a0 - x0;
        const float d1 = a1 - x1;
        const float d2 = nl - x2;
        const float nrm = sqrtf(d0 * d0 + d1 * d1 + d2 * d2);
        return -z * z * ud + 200.0f * nrm - 0.5f * r * r;
    };

    float local = iter_body(za, r_a);
    if (lane < N_ITERS - 64) {
        local += iter_body(zb, r_b);
    }

    // ---- loss butterfly reduce across the wave ----
    #pragma unroll
    for (int m = 32; m >= 1; m >>= 1) {
        local += __shfl_xor(local, m, 64);
    }

    if (lane == 0) {
        out[0] = local * (1.0f / (float)N_ITERS) - log_norm_term - log_var_term;
    }
}

extern "C" void kernel_launch(void* const* d_in, const int* in_sizes, int n_in,
                              void* d_out, int out_size, void* d_ws, size_t ws_size,
                              hipStream_t stream) {
    const float* x    = (const float*)d_in[0];
    const float* u0   = (const float*)d_in[1];
    const float* repa = (const float*)d_in[2];
    const float* W_e1 = (const float*)d_in[3];
    const float* b_e1 = (const float*)d_in[4];
    const float* W_e2 = (const float*)d_in[5];
    const float* b_e2 = (const float*)d_in[6];
    const float* W_x1 = (const float*)d_in[7];
    const float* b_x1 = (const float*)d_in[8];
    const float* W_x2 = (const float*)d_in[9];
    const float* b_x2 = (const float*)d_in[10];
    const float* W_n1 = (const float*)d_in[11];
    const float* b_n1 = (const float*)d_in[12];
    const float* W_n2 = (const float*)d_in[13];
    const float* b_n2 = (const float*)d_in[14];
    float* out = (float*)d_out;

    linearnet_fused<<<1, 64, 0, stream>>>(
        x, u0, repa,
        W_e1, b_e1, W_e2, b_e2,
        W_x1, b_x1, W_x2, b_x2,
        W_n1, b_n1, W_n2, b_n2,
        out);
}